// Round 4
// baseline (97.481 us; speedup 1.0000x reference)
//
#include <hip/hip_runtime.h>
#include <math.h>

#define NN 320      // particles
#define DD 64       // dim
#define NPAIRF ((double)(NN * (NN - 1) / 2))   // 51040

// ---------------------------------------------------------------------------
// Kernel 1: G = X * X^T (320x320 fp32). Tiny; L2-resident afterwards.
// ---------------------------------------------------------------------------
__global__ __launch_bounds__(NN) void gram_kernel(const float* __restrict__ data,
                                                  float* __restrict__ G) {
    __shared__ float rowa[DD];
    const int a = blockIdx.x;
    const int t = threadIdx.x;
    if (t < DD) rowa[t] = data[a * DD + t];
    __syncthreads();
    const float* rb = data + t * DD;
    float s = 0.f;
#pragma unroll
    for (int k = 0; k < DD; k += 4) {
        float4 x = *(const float4*)(rb + k);
        s = fmaf(rowa[k + 0], x.x, s);
        s = fmaf(rowa[k + 1], x.y, s);
        s = fmaf(rowa[k + 2], x.z, s);
        s = fmaf(rowa[k + 3], x.w, s);
    }
    G[a * NN + t] = s;
}

// ---------------------------------------------------------------------------
// Kernel 2: one block (512 thr) per TWO configurations. G rows are perm-
// independent, so each G load feeds 16 pair-elements (8 cols x 2 perms).
// 480 active threads = 40 column-strips (8 cols, VGPR-cached per perm) x 12
// row offsets; 26 iters x 12 rows + epilogue. G row for the NEXT iteration is
// prefetched into registers before computing the current one (1-deep pipeline,
// ~350 cyc of slack >> L2 latency). Full-matrix sweep (diagonal exactly 0),
// halve at the end.
// ---------------------------------------------------------------------------
__global__ __launch_bounds__(512, 4) void perm_kernel(const float* __restrict__ G,
                                                      const int* __restrict__ types,
                                                      const int* __restrict__ perms,
                                                      const float* __restrict__ fermp,
                                                      const float* __restrict__ bosp,
                                                      float* __restrict__ out) {
    __shared__ __align__(16) float apkA[NN * 4];   // perm A row pack {u, usn, -2u, w}
    __shared__ __align__(16) float apkB[NN * 4];   // perm B row pack
    __shared__ __align__(16) float colu[2][NN];
    __shared__ __align__(16) float colusn[2][NN];
    __shared__ __align__(16) float colvF[2][NN];
    __shared__ __align__(16) float colvB[2][NN];
    __shared__ double rsv[2][8], rsv2[2][8];

    const int blk = blockIdx.x;          // 0..500
    const int t   = threadIdx.x;
    const float Fv = *fermp;
    const float Bv = *bosp;

    const int cfgA = 2 * blk;                       // 0..1000
    const int cfgB = (2 * blk + 1 <= 1000) ? 2 * blk + 1 : 2 * blk;
    const int* prowA = (cfgA == 0) ? (const int*)nullptr : perms + (size_t)(cfgA - 1) * NN;
    const int* prowB = (cfgB == 0) ? (const int*)nullptr : perms + (size_t)(cfgB - 1) * NN;

    // Stage per-data-index quantities for both perms (scatter by a = perm[i]).
    for (int i = t; i < NN; i += 512) {
        const int ti = types[i];
        const float vF = (ti == 0) ? Fv : 1.0f;
        const float vB = (ti == 1) ? Bv : 1.0f;
        {
            const int a = prowA ? prowA[i] : i;
            float uv = 1.0f;
            if (a != i) {
                const int ta = types[a];
                uv = (ti == 0 && ta == 0) ? Fv : ((ti == 1 && ta == 1) ? Bv : 1.0f);
            }
            colu[0][a] = uv; colvF[0][a] = vF; colvB[0][a] = vB;
            apkA[4 * a + 0] = uv;
            apkA[4 * a + 2] = -2.0f * uv;
            apkA[4 * a + 3] = (float)ti;
        }
        {
            const int a = prowB ? prowB[i] : i;
            float uv = 1.0f;
            if (a != i) {
                const int ta = types[a];
                uv = (ti == 0 && ta == 0) ? Fv : ((ti == 1 && ta == 1) ? Bv : 1.0f);
            }
            colu[1][a] = uv; colvF[1][a] = vF; colvB[1][a] = vB;
            apkB[4 * a + 0] = uv;
            apkB[4 * a + 2] = -2.0f * uv;
            apkB[4 * a + 3] = (float)ti;
        }
    }
    __syncthreads();
    for (int a = t; a < NN; a += 512) {
        const float g = G[a * NN + a];
        const float uA = colu[0][a], uB = colu[1][a];
        const float usnA = uA * uA * g, usnB = uB * uB * g;
        colusn[0][a] = usnA; apkA[4 * a + 1] = usnA;
        colusn[1][a] = usnB; apkB[4 * a + 1] = usnB;
    }
    __syncthreads();

    float accvA = 0.0f, acc2A = 0.0f, accvB = 0.0f, acc2B = 0.0f;

    const int strip  = t % 40;        // 8-column strip
    const int rowoff = t / 40;        // 0..12 (12 -> idle)

    if (rowoff < 12) {
        const int col0 = strip * 8;
        // Column-side constants, VGPR-resident for the whole sweep (64 regs).
        const float4 uA0   = *(const float4*)(&colu[0][col0]);
        const float4 uA1   = *(const float4*)(&colu[0][col0 + 4]);
        const float4 snA0  = *(const float4*)(&colusn[0][col0]);
        const float4 snA1  = *(const float4*)(&colusn[0][col0 + 4]);
        const float4 vFA0  = *(const float4*)(&colvF[0][col0]);
        const float4 vFA1  = *(const float4*)(&colvF[0][col0 + 4]);
        const float4 vBA0  = *(const float4*)(&colvB[0][col0]);
        const float4 vBA1  = *(const float4*)(&colvB[0][col0 + 4]);
        const float4 uB0   = *(const float4*)(&colu[1][col0]);
        const float4 uB1   = *(const float4*)(&colu[1][col0 + 4]);
        const float4 snB0  = *(const float4*)(&colusn[1][col0]);
        const float4 snB1  = *(const float4*)(&colusn[1][col0 + 4]);
        const float4 vFB0  = *(const float4*)(&colvF[1][col0]);
        const float4 vFB1  = *(const float4*)(&colvF[1][col0 + 4]);
        const float4 vBB0  = *(const float4*)(&colvB[1][col0]);
        const float4 vBB1  = *(const float4*)(&colvB[1][col0 + 4]);

        const float* gp   = G + rowoff * NN + col0;
        const float* appA = apkA + 4 * rowoff;
        const float* appB = apkB + 4 * rowoff;

        float4 g0 = *(const float4*)gp;
        float4 g1 = *(const float4*)(gp + 4);

#define PAIR(ACCV, ACC2, AP, WA, GC, UBC, SNBC, VFC, VBC)        \
        {                                                        \
            const float tt  = (UBC) * (GC);                      \
            const float sab = (AP).y + (SNBC);                   \
            const float d2  = fmaf((AP).z, tt, sab);             \
            const float dd  = __builtin_amdgcn_sqrtf(fabsf(d2)); \
            const float vsl = (WA) ? (VBC) : (VFC);              \
            ACCV = fmaf(vsl, dd, ACCV);                          \
            ACC2 += fabsf(d2);                                   \
        }

#define ROW2()                                                           \
        {                                                                \
            const float4 apA = *(const float4*)appA;                     \
            const float4 apB = *(const float4*)appB;                     \
            const bool wA = (apA.w != 0.0f);                             \
            const bool wB = (apB.w != 0.0f);                             \
            PAIR(accvA, acc2A, apA, wA, g0.x, uA0.x, snA0.x, vFA0.x, vBA0.x) \
            PAIR(accvA, acc2A, apA, wA, g0.y, uA0.y, snA0.y, vFA0.y, vBA0.y) \
            PAIR(accvA, acc2A, apA, wA, g0.z, uA0.z, snA0.z, vFA0.z, vBA0.z) \
            PAIR(accvA, acc2A, apA, wA, g0.w, uA0.w, snA0.w, vFA0.w, vBA0.w) \
            PAIR(accvA, acc2A, apA, wA, g1.x, uA1.x, snA1.x, vFA1.x, vBA1.x) \
            PAIR(accvA, acc2A, apA, wA, g1.y, uA1.y, snA1.y, vFA1.y, vBA1.y) \
            PAIR(accvA, acc2A, apA, wA, g1.z, uA1.z, snA1.z, vFA1.z, vBA1.z) \
            PAIR(accvA, acc2A, apA, wA, g1.w, uA1.w, snA1.w, vFA1.w, vBA1.w) \
            PAIR(accvB, acc2B, apB, wB, g0.x, uB0.x, snB0.x, vFB0.x, vBB0.x) \
            PAIR(accvB, acc2B, apB, wB, g0.y, uB0.y, snB0.y, vFB0.y, vBB0.y) \
            PAIR(accvB, acc2B, apB, wB, g0.z, uB0.z, snB0.z, vFB0.z, vBB0.z) \
            PAIR(accvB, acc2B, apB, wB, g0.w, uB0.w, snB0.w, vFB0.w, vBB0.w) \
            PAIR(accvB, acc2B, apB, wB, g1.x, uB1.x, snB1.x, vFB1.x, vBB1.x) \
            PAIR(accvB, acc2B, apB, wB, g1.y, uB1.y, snB1.y, vFB1.y, vBB1.y) \
            PAIR(accvB, acc2B, apB, wB, g1.z, uB1.z, snB1.z, vFB1.z, vBB1.z) \
            PAIR(accvB, acc2B, apB, wB, g1.w, uB1.w, snB1.w, vFB1.w, vBB1.w) \
        }

        // 26 iterations x 12 rows cover rows 0..311; G prefetched 1 iter ahead.
        for (int it = 0; it < 26; ++it) {
            gp += 12 * NN;
            const float4 n0 = *(const float4*)gp;        // next row block
            const float4 n1 = *(const float4*)(gp + 4);  // (last: rows 312..323,
            ROW2();                                      //  garbage for rowoff>=8,
            appA += 48; appB += 48;                      //  never consumed)
            g0 = n0; g1 = n1;
        }
        // Epilogue: rows 312..319 (rowoff 0..7) — uses last prefetched g.
        if (rowoff < 8) {
            ROW2();
        }
#undef ROW2
#undef PAIR
    }

    // Reduce both configs: f32 lanes -> f64, wave shuffle, cross-wave via LDS.
    double svA = (double)accvA, sv2A = (double)acc2A;
    double svB = (double)accvB, sv2B = (double)acc2B;
    for (int off = 32; off; off >>= 1) {
        svA  += __shfl_down(svA,  off, 64);
        sv2A += __shfl_down(sv2A, off, 64);
        svB  += __shfl_down(svB,  off, 64);
        sv2B += __shfl_down(sv2B, off, 64);
    }
    const int wid = t >> 6, lane = t & 63;
    if (lane == 0) {
        rsv[0][wid] = svA; rsv2[0][wid] = sv2A;
        rsv[1][wid] = svB; rsv2[1][wid] = sv2B;
    }
    __syncthreads();
    if (t == 0) {
        double SA = 0.0, S2A = 0.0, SB = 0.0, S2B = 0.0;
#pragma unroll
        for (int i = 0; i < 8; ++i) {
            SA += rsv[0][i]; S2A += rsv2[0][i];
            SB += rsv[1][i]; S2B += rsv2[1][i];
        }
        SA *= 0.5; S2A *= 0.5;   // full-matrix sweep double-counts pairs
        SB *= 0.5; S2B *= 0.5;
        out[cfgA] = (float)((S2A - SA * SA / NPAIRF) / (NPAIRF - 1.0));
        if (2 * blk + 1 <= 1000)
            out[cfgB] = (float)((S2B - SB * SB / NPAIRF) / (NPAIRF - 1.0));
    }
}

extern "C" void kernel_launch(void* const* d_in, const int* in_sizes, int n_in,
                              void* d_out, int out_size, void* d_ws, size_t ws_size,
                              hipStream_t stream) {
    const float* data  = (const float*)d_in[0];
    const float* fermp = (const float*)d_in[1];
    const float* bosp  = (const float*)d_in[2];
    const int*   types = (const int*)d_in[3];
    const int*   perms = (const int*)d_in[4];
    float* out = (float*)d_out;
    float* G   = (float*)d_ws;   // 320*320*4 = 409600 B

    gram_kernel<<<NN, NN, 0, stream>>>(data, G);
    perm_kernel<<<501, 512, 0, stream>>>(G, types, perms, fermp, bosp, out);
}

// Round 5
// 96.333 us; speedup vs baseline: 1.0119x; 1.0119x over previous
//
#include <hip/hip_runtime.h>
#include <hip/hip_fp16.h>
#include <math.h>

#define NN 320      // particles
#define DD 64       // dim
#define MPAIR 51040.0   // N*(N-1)/2

// ---------------------------------------------------------------------------
// K1: fused Gram + distance tables. Block a (320 thr, thread = column b):
// T[a][b] = half2(Pp, Pm) with Pp = ||x_a - x_b||, Pm = ||x_a + x_b|| — the
// only two distances possible for pair (a,b) across ALL configs, since every
// permuted row is +-x_a (u in {Fv,Bv,1} = {-1,+1}).
// Diagonal: g == sna == snb bitwise (identical FMA chains) => Pp_aa = 0 exact.
// ---------------------------------------------------------------------------
__global__ __launch_bounds__(320) void tables_kernel(const float* __restrict__ data,
                                                     __half2* __restrict__ T) {
    __shared__ float rowa[DD];
    const int a = blockIdx.x, b = threadIdx.x;
    if (b < DD) rowa[b] = data[a * DD + b];
    __syncthreads();
    const float* xb = data + b * DD;
    float g = 0.f, snb = 0.f, sna = 0.f;
#pragma unroll
    for (int k = 0; k < DD; k += 4) {
        const float4 xv = *(const float4*)(xb + k);
        const float4 av = *(const float4*)(rowa + k);
        g   = fmaf(av.x, xv.x, g);   g   = fmaf(av.y, xv.y, g);
        g   = fmaf(av.z, xv.z, g);   g   = fmaf(av.w, xv.w, g);
        snb = fmaf(xv.x, xv.x, snb); snb = fmaf(xv.y, xv.y, snb);
        snb = fmaf(xv.z, xv.z, snb); snb = fmaf(xv.w, xv.w, snb);
        sna = fmaf(av.x, av.x, sna); sna = fmaf(av.y, av.y, sna);
        sna = fmaf(av.z, av.z, sna); sna = fmaf(av.w, av.w, sna);
    }
    const float s  = sna + snb;
    const float Pp = sqrtf(fmaxf(s - 2.f * g, 0.f));
    const float Pm = sqrtf(fmaxf(s + 2.f * g, 0.f));
    T[a * NN + b] = __floats2half2_rn(Pp, Pm);
}

// ---------------------------------------------------------------------------
// K2: one block (512 thr, 8 waves) per FOUR configurations (table loads shared
// 4 ways). Full-matrix sweep: per element per config the summand is
//   sel = (s_a==s_b) ? Pp : Pm;  vs = f_row ? (f_col?Fv:1) : (f_col?1:Bv);
//   SV += vs*sel;  SV2 += sel*sel        (sigma^2 = 1)
// — 5 VALU ops, NO sqrt. Diagonal contributes exactly 0; halve at the end.
// Thread owns a fixed 4-column strip (col consts in VGPRs); 6 rows/iter.
// ---------------------------------------------------------------------------
__global__ __launch_bounds__(512, 4) void sweep_kernel(const __half2* __restrict__ T,
                                                       const int* __restrict__ types,
                                                       const int* __restrict__ perms,
                                                       const float* __restrict__ fermp,
                                                       const float* __restrict__ bosp,
                                                       float* __restrict__ out) {
    __shared__ __align__(16) float rowpk[NN][8];   // per data-index a: {s,f} x 4 cfg
    __shared__ float redv[8][4], red2[8][4];
    const int t = threadIdx.x;
    const float Fv = *fermp;
    const float Bv = *bosp;
    const int cfg0 = blockIdx.x * 4;

    // Stage per-config sign s_a = u_a and slot-fermion flag f_a (scatter by a=perm[i]).
    for (int c = 0; c < 4; ++c) {
        int cfg = cfg0 + c; if (cfg > 1000) cfg = 1000;   // dup tail, writes guarded
        const int* prow = (cfg == 0) ? (const int*)nullptr
                                     : perms + (size_t)(cfg - 1) * NN;
        for (int i = t; i < NN; i += 512) {
            const int a  = prow ? prow[i] : i;
            const int ti = types[i];
            float u = 1.f;
            if (a != i) {
                const int ta = types[a];
                u = (ti == 0 && ta == 0) ? Fv : ((ti == 1 && ta == 1) ? Bv : 1.f);
            }
            rowpk[a][2 * c]     = u;                       // +-1
            rowpk[a][2 * c + 1] = (ti == 0) ? 1.f : 0.f;   // slot is fermion
        }
    }
    __syncthreads();

    const int strip = t % 80, rowoff = t / 80;   // 480 active, 6 rows/iter
    float accv[4] = {0, 0, 0, 0}, acc2[4] = {0, 0, 0, 0};

    if (rowoff < 6) {
        const int col0 = strip * 4;
        // Column-side constants, VGPR-resident for the whole sweep.
        float sb[4][4], vF[4][4], vB[4][4];
#pragma unroll
        for (int c = 0; c < 4; ++c)
#pragma unroll
            for (int j = 0; j < 4; ++j) {
                const float s = rowpk[col0 + j][2 * c];
                const float f = rowpk[col0 + j][2 * c + 1];
                sb[c][j] = s;
                vF[c][j] = (f != 0.f) ? Fv : 1.f;   // used when row slot is fermion
                vB[c][j] = (f != 0.f) ? 1.f : Bv;   // used when row slot is boson
            }

        const __half2* gp = T + rowoff * NN + col0;
        float4 gcur = *(const float4*)gp;           // 4 cols x half2(Pp,Pm) = 16 B
        for (int row = rowoff; row < NN; row += 6) {
            gp += 6 * NN;
            const float4 gnext = *(const float4*)gp;   // prefetch; past-end lands in ws slack
            const __half2* hp = (const __half2*)&gcur;
            float2 P[4];
            P[0] = __half22float2(hp[0]); P[1] = __half22float2(hp[1]);
            P[2] = __half22float2(hp[2]); P[3] = __half22float2(hp[3]);
            const float4 rp0 = *(const float4*)&rowpk[row][0];
            const float4 rp1 = *(const float4*)&rowpk[row][4];
            const float sa[4] = {rp0.x, rp0.z, rp1.x, rp1.z};
            const float fa[4] = {rp0.y, rp0.w, rp1.y, rp1.w};
#pragma unroll
            for (int c = 0; c < 4; ++c) {
                const bool frow = (fa[c] != 0.f);
#pragma unroll
                for (int j = 0; j < 4; ++j) {
                    const float sel = (sa[c] == sb[c][j]) ? P[j].x : P[j].y;
                    const float vs  = frow ? vF[c][j] : vB[c][j];
                    accv[c] = fmaf(vs, sel, accv[c]);
                    acc2[c] = fmaf(sel, sel, acc2[c]);
                }
            }
            gcur = gnext;
        }
    }

    // Reduce: f32 lane partials -> wave shuffle -> cross-wave LDS -> f64 combine.
#pragma unroll
    for (int c = 0; c < 4; ++c)
        for (int off = 32; off; off >>= 1) {
            accv[c] += __shfl_down(accv[c], off, 64);
            acc2[c] += __shfl_down(acc2[c], off, 64);
        }
    const int wid = t >> 6, lane = t & 63;
    if (lane == 0)
#pragma unroll
        for (int c = 0; c < 4; ++c) { redv[wid][c] = accv[c]; red2[wid][c] = acc2[c]; }
    __syncthreads();
    if (t < 4) {
        double sv = 0.0, s2 = 0.0;
#pragma unroll
        for (int w = 0; w < 8; ++w) { sv += redv[w][t]; s2 += red2[w][t]; }
        sv *= 0.5;   // full-matrix sweep double-counts unordered pairs
        s2 *= 0.5;
        const int cfg = cfg0 + t;
        if (cfg <= 1000)
            out[cfg] = (float)((s2 - sv * sv / MPAIR) / (MPAIR - 1.0));
    }
}

extern "C" void kernel_launch(void* const* d_in, const int* in_sizes, int n_in,
                              void* d_out, int out_size, void* d_ws, size_t ws_size,
                              hipStream_t stream) {
    const float* data  = (const float*)d_in[0];
    const float* fermp = (const float*)d_in[1];
    const float* bosp  = (const float*)d_in[2];
    const int*   types = (const int*)d_in[3];
    const int*   perms = (const int*)d_in[4];
    float* out = (float*)d_out;
    __half2* T = (__half2*)d_ws;   // 320*320*4 B = 409,600 B (+ slack for prefetch)

    tables_kernel<<<NN, NN, 0, stream>>>(data, T);
    sweep_kernel<<<251, 512, 0, stream>>>(T, types, perms, fermp, bosp, out);
}